// Round 3
// baseline (10452.544 us; speedup 1.0000x reference)
//
#include <hip/hip_runtime.h>

#define DD 1024
#define HALO 32
#define IMG 1152               // floats per component image; 1152*4B = 9*512B
#define HALF_DT_F 0.05f
#define CG_ITERS_N 20

// XOR swizzle on float index (byte' = byte ^ (((byte>>7)&3)<<4)).
// Involution; preserves 16B alignment; commutes with offsets that are
// multiples of 128 floats (IMG, row base, +-DD halo shifts all qualify).
__device__ __forceinline__ int swzf(int f) { return f ^ (((f >> 5) & 3) << 2); }

__device__ __forceinline__ void fence_lds() {
    asm volatile("s_waitcnt lgkmcnt(0)" ::: "memory");
}

__device__ __forceinline__ float wave_sum(float v) {
#pragma unroll
    for (int m = 32; m >= 1; m >>= 1)
        v += __shfl_xor(v, m, 64);
    return v;
}

// tap -> coupling-weight index, -1 if not a tap. Constant-folds after unroll.
__device__ constexpr int tapidx(int a) {
    return a == 1 ? 0 : a == 2 ? 1 : a == 3 ? 2 : a == 4 ? 3 : a == 5 ? 4 :
           a == 6 ? 5 : a == 8 ? 6 : a == 10 ? 7 : a == 12 ? 8 :
           a == 16 ? 9 : a == 20 ? 10 : -1;
}

// Streaming H-apply on this lane's 16 elements. Reads 14 swizzled float4
// chunks; each chunk is scatter-accumulated into H[16] immediately (no
// materialized window -> low register peak). Also extracts p = window center.
__device__ __forceinline__ void hmat_acc(const float* lds, const int ra[14], int cOff,
                                         const float cw[11], const float diag[16],
                                         float H[16], float p[16]) {
#pragma unroll
    for (int i = 0; i < 16; ++i) H[i] = 0.f;
#pragma unroll
    for (int k = 0; k < 14; ++k) {
        float4 v = *reinterpret_cast<const float4*>(&lds[ra[k] + cOff]);
        float f[4] = {v.x, v.y, v.z, v.w};
#pragma unroll
        for (int q = 0; q < 4; ++q) {
            const int m = 4 * k - 20 + q;          // offset relative to d0
            if (m >= 0 && m < 16) p[m] = f[q];
#pragma unroll
            for (int i = 0; i < 16; ++i) {
                const int d = i - m;
                if (d == 0) {
                    H[i] += diag[i] * f[q];
                } else {
                    const int a = d < 0 ? -d : d;
                    const int j = tapidx(a);
                    if (j >= 0) H[i] -= cw[j] * f[q];
                }
            }
        }
    }
}

// Store this lane's 16 elements (both components) + halo copies (lanes 0,1,62,63).
__device__ __forceinline__ void store_row(float* lds, const int wa[4], const int ha[4],
                                          bool hh, const float vr[16], const float vi[16]) {
#pragma unroll
    for (int j = 0; j < 4; ++j) {
        float4 a = make_float4(vr[4 * j], vr[4 * j + 1], vr[4 * j + 2], vr[4 * j + 3]);
        float4 b = make_float4(vi[4 * j], vi[4 * j + 1], vi[4 * j + 2], vi[4 * j + 3]);
        *reinterpret_cast<float4*>(&lds[wa[j]]) = a;
        *reinterpret_cast<float4*>(&lds[wa[j] + IMG]) = b;
        if (hh) {
            *reinterpret_cast<float4*>(&lds[ha[j]]) = a;
            *reinterpret_cast<float4*>(&lds[ha[j] + IMG]) = b;
        }
    }
}

__global__ void __launch_bounds__(64, 2)
cayley_kernel(const float* __restrict__ psi_r, const float* __restrict__ psi_i,
              const float* __restrict__ alpha, const float* __restrict__ sw,
              const float* __restrict__ potential, float* __restrict__ out) {
    __shared__ __align__(16) float lds[2 * IMG];   // one row, both components

    const int l = threadIdx.x;     // one wave per block; wave owns one row
    const int row = blockIdx.x;

    const float w0 = sw[0], w1 = sw[1], w2 = sw[2];
    const float cw[11] = {w0, w0 + w1, w0, w0 + w1 + w2, w0, w1, w1 + w2, w1, w2, w2, w2};
    const float dadd = 10.0f * (w0 + w1 + w2);

    // Loop-invariant swizzled LDS float-index addresses (component 0).
    int wa[4], ra[14];
#pragma unroll
    for (int j = 0; j < 4; ++j) wa[j] = swzf(HALO + 16 * l + 4 * j);
#pragma unroll
    for (int k = 0; k < 14; ++k) ra[k] = swzf(HALO - 20 + 16 * l + 4 * k);
    const bool hh = (l < 2) || (l >= 62);
    int ha[4] = {0, 0, 0, 0};
    if (l < 2) {
#pragma unroll
        for (int j = 0; j < 4; ++j) ha[j] = swzf(HALO + DD + 16 * l + 4 * j);
    } else if (l >= 62) {
#pragma unroll
        for (int j = 0; j < 4; ++j) ha[j] = swzf(HALO + 16 * l - DD + 4 * j);
    }

    // --- global loads ---
    const size_t goff = (size_t)row * DD + 16 * l;
    float prv[16], piv[16], diag[16];
#pragma unroll
    for (int j = 0; j < 4; ++j) {
        float4 a = *reinterpret_cast<const float4*>(psi_r + goff + 4 * j);
        float4 b = *reinterpret_cast<const float4*>(psi_i + goff + 4 * j);
        float4 d = *reinterpret_cast<const float4*>(potential + 16 * l + 4 * j);
        prv[4 * j] = a.x; prv[4 * j + 1] = a.y; prv[4 * j + 2] = a.z; prv[4 * j + 3] = a.w;
        piv[4 * j] = b.x; piv[4 * j + 1] = b.y; piv[4 * j + 2] = b.z; piv[4 * j + 3] = b.w;
        diag[4 * j] = d.x + dadd; diag[4 * j + 1] = d.y + dadd;
        diag[4 * j + 2] = d.z + dadd; diag[4 * j + 3] = d.w + dadd;
    }

    // --- intensity mean (recompute intensity later; don't hold 16 extra regs) ---
    float isum = 0.f;
#pragma unroll
    for (int i = 0; i < 16; ++i) isum += prv[i] * prv[i] + piv[i] * piv[i];
    const float inv_mean = 1.0f / (wave_sum(isum) * (1.0f / DD) + 1e-8f);

    // --- nonlinear phase rotation, in place ---
#pragma unroll
    for (int j = 0; j < 4; ++j) {
        float4 c = *reinterpret_cast<const float4*>(alpha + 16 * l + 4 * j);
        float av[4] = {c.x, c.y, c.z, c.w};
#pragma unroll
        for (int q = 0; q < 4; ++q) {
            const int i = 4 * j + q;
            const float ph = av[q] * ((prv[i] * prv[i] + piv[i] * piv[i]) * inv_mean);
            float s, cc;
            sincosf(ph, &s, &cc);
            const float nr = prv[i] * cc - piv[i] * s;
            const float ni = prv[i] * s + piv[i] * cc;
            prv[i] = nr; piv[i] = ni;
        }
    }

    store_row(lds, wa, ha, hh, prv, piv);
    fence_lds();

    // --- rhs = (I - i*dt/2*H) rot ;  r = p = rhs ; x = 0 ---
    float Hr[16], Hi[16], pr_[16], pi_[16];
    hmat_acc(lds, ra, 0, cw, diag, Hr, pr_);
    hmat_acc(lds, ra, IMG, cw, diag, Hi, pi_);

    float xr[16], xi[16], rr[16], ri[16];
    float rsum = 0.f;
#pragma unroll
    for (int i = 0; i < 16; ++i) {
        xr[i] = 0.f; xi[i] = 0.f;
        rr[i] = prv[i] + HALF_DT_F * Hi[i];
        ri[i] = piv[i] - HALF_DT_F * Hr[i];
        pr_[i] = rr[i]; pi_[i] = ri[i];
        rsum += rr[i] * rr[i] + ri[i] * ri[i];
    }
    float rs = wave_sum(rsum);

    store_row(lds, wa, ha, hh, pr_, pi_);
    fence_lds();

    // --- CG: 20 fixed iterations, fully wave-local, zero barriers ---
#pragma unroll 1
    for (int it = 0; it < CG_ITERS_N; ++it) {
        // H(p) per component; p re-extracted from the LDS window centers
        // (not carried in registers across the iteration boundary).
        hmat_acc(lds, ra, 0, cw, diag, Hr, pr_);
        hmat_acc(lds, ra, IMG, cw, diag, Hi, pi_);

        // pAp = sum p.(A p) with A p = (pr - hdt*Hi, pi + hdt*Hr), Ap never materialized.
        float pap = 0.f;
#pragma unroll
        for (int i = 0; i < 16; ++i)
            pap += pr_[i] * pr_[i] + pi_[i] * pi_[i]
                 - HALF_DT_F * (pr_[i] * Hi[i] - pi_[i] * Hr[i]);
        const float pAp = wave_sum(pap);
        const float al = rs / (pAp + 1e-12f);
        const float alh = al * HALF_DT_F;

        float rnew = 0.f;
#pragma unroll
        for (int i = 0; i < 16; ++i) {
            xr[i] += al * pr_[i];
            xi[i] += al * pi_[i];
            rr[i] = rr[i] - al * pr_[i] + alh * Hi[i];   // r -= al*Ap (fused)
            ri[i] = ri[i] - al * pi_[i] - alh * Hr[i];
            rnew += rr[i] * rr[i] + ri[i] * ri[i];
        }
        const float rs_new = wave_sum(rnew);
        const float beta = rs_new / (rs + 1e-12f);
        rs = rs_new;
#pragma unroll
        for (int i = 0; i < 16; ++i) {
            pr_[i] = rr[i] + beta * pr_[i];
            pi_[i] = ri[i] + beta * pi_[i];
        }
        store_row(lds, wa, ha, hh, pr_, pi_);
        fence_lds();
    }

    // --- write x as [.., D, 2] real pairs ---
    float* op = out + 2 * goff;
#pragma unroll
    for (int j = 0; j < 8; ++j) {
        *reinterpret_cast<float4*>(op + 4 * j) =
            make_float4(xr[2 * j], xi[2 * j], xr[2 * j + 1], xi[2 * j + 1]);
    }
}

extern "C" void kernel_launch(void* const* d_in, const int* in_sizes, int n_in,
                              void* d_out, int out_size, void* d_ws, size_t ws_size,
                              hipStream_t stream) {
    const float* psi_r = (const float*)d_in[0];
    const float* psi_i = (const float*)d_in[1];
    const float* alpha = (const float*)d_in[2];
    const float* sw = (const float*)d_in[3];
    const float* pot = (const float*)d_in[4];
    float* out = (float*)d_out;
    const int rows = in_sizes[0] / DD;   // B*S = 8192
    cayley_kernel<<<dim3(rows), dim3(64), 0, stream>>>(psi_r, psi_i, alpha, sw, pot, out);
}

// Round 4
// 411.092 us; speedup vs baseline: 25.4263x; 25.4263x over previous
//
#include <hip/hip_runtime.h>

#define DD 1024
#define HALO 32
#define IMG 1088                 // HALO+DD+HALO floats = 17*64 -> swizzle-compatible
#define ROWSTR (2 * IMG)         // floats per row image (both components)
#define HALF_DT_F 0.05f
#define CG_ITERS_N 20

// XOR swizzle on float index (byte' = byte ^ (((byte>>7)&1)<<4)).
// Involution; preserves 16B alignment; commutes with any offset that is a
// multiple of 64 floats (256B): IMG, ROWSTR, +-DD all qualify. For this
// kernel's 32B-lane-stride float4 accesses it spreads every 8 consecutive
// lanes across all 8 LDS bank groups (enumerated: {12,20,28,0,8,16,24,4}).
__device__ __forceinline__ int swzf(int f) { return f ^ (((f >> 5) & 1) << 2); }

__device__ __forceinline__ float wave_red(float v) {
#pragma unroll
    for (int m = 32; m >= 1; m >>= 1)
        v += __shfl_xor(v, m, 64);
    return v;
}

// Row-wide (128-thread, 2-wave) sum; exactly one barrier. Caller alternates
// `red` buffers so consecutive reductions never reuse a live buffer.
__device__ __forceinline__ float row_sum(float v, float* red, int wave, int rw) {
    v = wave_red(v);
    if ((threadIdx.x & 63) == 0) red[wave] = v;
    __syncthreads();
    return red[2 * rw] + red[2 * rw + 1];
}

// H on this thread's 8 elements. Window = 48 floats [d0-20, d0+28); the 8
// center values are this thread's own p (passed in regs) -> only 10 b128
// LDS reads per component.
__device__ __forceinline__ void hmat8(const float* lds, const int ra[10], int cOff,
                                      const float cw[11], const float diag[8],
                                      const float pc[8], float H[8]) {
    float win[48];
#pragma unroll
    for (int k = 0; k < 5; ++k) {
        float4 v = *reinterpret_cast<const float4*>(&lds[ra[k] + cOff]);
        win[4 * k + 0] = v.x; win[4 * k + 1] = v.y;
        win[4 * k + 2] = v.z; win[4 * k + 3] = v.w;
    }
#pragma unroll
    for (int i = 0; i < 8; ++i) win[20 + i] = pc[i];
#pragma unroll
    for (int k = 0; k < 5; ++k) {
        float4 v = *reinterpret_cast<const float4*>(&lds[ra[5 + k] + cOff]);
        win[28 + 4 * k + 0] = v.x; win[28 + 4 * k + 1] = v.y;
        win[28 + 4 * k + 2] = v.z; win[28 + 4 * k + 3] = v.w;
    }
    constexpr int taps[11] = {1, 2, 3, 4, 5, 6, 8, 10, 12, 16, 20};
#pragma unroll
    for (int i = 0; i < 8; ++i) {
        float acc = diag[i] * win[20 + i];
#pragma unroll
        for (int j = 0; j < 11; ++j)
            acc -= cw[j] * (win[20 + i - taps[j]] + win[20 + i + taps[j]]);
        H[i] = acc;
    }
}

// Store this thread's 8 elements (both components) + halo copies
// (row-threads 0..3 duplicate to the right halo, 124..127 to the left).
__device__ __forceinline__ void store_row8(float* lds, const int wa[2], const int ha[2],
                                           bool hh, const float vr[8], const float vi[8]) {
#pragma unroll
    for (int j = 0; j < 2; ++j) {
        float4 a = make_float4(vr[4 * j], vr[4 * j + 1], vr[4 * j + 2], vr[4 * j + 3]);
        float4 b = make_float4(vi[4 * j], vi[4 * j + 1], vi[4 * j + 2], vi[4 * j + 3]);
        *reinterpret_cast<float4*>(&lds[wa[j]]) = a;
        *reinterpret_cast<float4*>(&lds[wa[j] + IMG]) = b;
        if (hh) {
            *reinterpret_cast<float4*>(&lds[ha[j]]) = a;
            *reinterpret_cast<float4*>(&lds[ha[j] + IMG]) = b;
        }
    }
}

__global__ void __launch_bounds__(256, 2)
cayley_kernel(const float* __restrict__ psi_r, const float* __restrict__ psi_i,
              const float* __restrict__ alpha, const float* __restrict__ sw,
              const float* __restrict__ potential, float* __restrict__ out) {
    __shared__ __align__(16) float lds[2 * ROWSTR];   // 2 rows x 2 comps
    __shared__ float red0[4], red1[4];

    const int t = threadIdx.x;
    const int u = t & 127;         // row-local thread: owns elements [8u, 8u+8)
    const int rw = t >> 7;         // row within block (0/1)
    const int wave = t >> 6;
    const int rb = rw * ROWSTR;
    const int row = (blockIdx.x << 1) + rw;

    const float w0 = sw[0], w1 = sw[1], w2 = sw[2];   // uniform -> SGPRs
    const float cw[11] = {w0, w0 + w1, w0, w0 + w1 + w2, w0, w1, w1 + w2, w1, w2, w2, w2};
    const float dadd = 10.0f * (w0 + w1 + w2);

    // Loop-invariant swizzled LDS addresses (float indices, component 0).
    // Window chunks skip the two center float4s (k=5,6 of the 12-chunk span).
    int wa[2], ra[10];
#pragma unroll
    for (int j = 0; j < 2; ++j) wa[j] = swzf(rb + HALO + 8 * u + 4 * j);
#pragma unroll
    for (int k = 0; k < 5; ++k) {
        ra[k]     = swzf(rb + HALO + 8 * u - 20 + 4 * k);        // left 20 floats
        ra[5 + k] = swzf(rb + HALO + 8 * u + 8 + 4 * k);         // right 20 floats
    }
    const bool hh = (u < 4) || (u >= 124);
    int ha[2] = {0, 0};
    if (u < 4) {
#pragma unroll
        for (int j = 0; j < 2; ++j) ha[j] = swzf(rb + HALO + 8 * u + DD + 4 * j);
    } else if (u >= 124) {
#pragma unroll
        for (int j = 0; j < 2; ++j) ha[j] = swzf(rb + HALO + 8 * u - DD + 4 * j);
    }

    // --- global loads: 8 contiguous elements per thread ---
    const size_t goff = (size_t)row * DD + 8 * u;
    float prv[8], piv[8], diag[8];
#pragma unroll
    for (int j = 0; j < 2; ++j) {
        float4 a = *reinterpret_cast<const float4*>(psi_r + goff + 4 * j);
        float4 b = *reinterpret_cast<const float4*>(psi_i + goff + 4 * j);
        float4 d = *reinterpret_cast<const float4*>(potential + 8 * u + 4 * j);
        prv[4 * j] = a.x; prv[4 * j + 1] = a.y; prv[4 * j + 2] = a.z; prv[4 * j + 3] = a.w;
        piv[4 * j] = b.x; piv[4 * j + 1] = b.y; piv[4 * j + 2] = b.z; piv[4 * j + 3] = b.w;
        diag[4 * j] = d.x + dadd; diag[4 * j + 1] = d.y + dadd;
        diag[4 * j + 2] = d.z + dadd; diag[4 * j + 3] = d.w + dadd;
    }

    // --- intensity mean over the row ---
    float isum = 0.f;
#pragma unroll
    for (int i = 0; i < 8; ++i) isum += prv[i] * prv[i] + piv[i] * piv[i];
    const float tot = row_sum(isum, red0, wave, rw);
    const float inv_mean = 1.0f / (tot * (1.0f / DD) + 1e-8f);

    // --- nonlinear phase rotation (in place; rot stays in prv/piv) ---
#pragma unroll
    for (int j = 0; j < 2; ++j) {
        float4 c = *reinterpret_cast<const float4*>(alpha + 8 * u + 4 * j);
        float av[4] = {c.x, c.y, c.z, c.w};
#pragma unroll
        for (int q = 0; q < 4; ++q) {
            const int i = 4 * j + q;
            const float ph = av[q] * ((prv[i] * prv[i] + piv[i] * piv[i]) * inv_mean);
            float s, cc;
            sincosf(ph, &s, &cc);
            const float nr = prv[i] * cc - piv[i] * s;
            const float ni = prv[i] * s + piv[i] * cc;
            prv[i] = nr; piv[i] = ni;
        }
    }

    store_row8(lds, wa, ha, hh, prv, piv);
    __syncthreads();

    // --- rhs = (I - i*dt/2*H) rot ; r = p = rhs ; x = 0 ---
    float Hr[8], Hi[8];
    hmat8(lds, ra, 0, cw, diag, prv, Hr);
    hmat8(lds, ra, IMG, cw, diag, piv, Hi);

    float xr[8], xi[8], rr[8], ri[8], pr_[8], pi_[8];
    float rsum = 0.f;
#pragma unroll
    for (int i = 0; i < 8; ++i) {
        xr[i] = 0.f; xi[i] = 0.f;
        rr[i] = prv[i] + HALF_DT_F * Hi[i];
        ri[i] = piv[i] - HALF_DT_F * Hr[i];
        pr_[i] = rr[i]; pi_[i] = ri[i];
        rsum += rr[i] * rr[i] + ri[i] * ri[i];
    }
    float rs = row_sum(rsum, red1, wave, rw);   // barrier fences hmat reads

    store_row8(lds, wa, ha, hh, pr_, pi_);
    __syncthreads();

    // --- CG: 20 fixed iterations, 3 barriers each ---
#pragma unroll 1
    for (int it = 0; it < CG_ITERS_N; ++it) {
        hmat8(lds, ra, 0, cw, diag, pr_, Hr);
        hmat8(lds, ra, IMG, cw, diag, pi_, Hi);

        // pAp with Ap = (pr - hdt*Hi, pi + hdt*Hr), never materialized.
        float pap = 0.f;
#pragma unroll
        for (int i = 0; i < 8; ++i)
            pap += pr_[i] * pr_[i] + pi_[i] * pi_[i]
                 - HALF_DT_F * (pr_[i] * Hi[i] - pi_[i] * Hr[i]);
        const float pAp = row_sum(pap, red0, wave, rw);   // barrier #1 (fences window reads)
        const float al = rs / (pAp + 1e-12f);
        const float alh = al * HALF_DT_F;

        float rnew = 0.f;
#pragma unroll
        for (int i = 0; i < 8; ++i) {
            xr[i] += al * pr_[i];
            xi[i] += al * pi_[i];
            rr[i] = rr[i] - al * pr_[i] + alh * Hi[i];
            ri[i] = ri[i] - al * pi_[i] - alh * Hr[i];
            rnew += rr[i] * rr[i] + ri[i] * ri[i];
        }
        const float rs_new = row_sum(rnew, red1, wave, rw);   // barrier #2
        const float beta = rs_new / (rs + 1e-12f);
        rs = rs_new;
#pragma unroll
        for (int i = 0; i < 8; ++i) {
            pr_[i] = rr[i] + beta * pr_[i];
            pi_[i] = ri[i] + beta * pi_[i];
        }
        store_row8(lds, wa, ha, hh, pr_, pi_);
        __syncthreads();                                      // barrier #3
    }

    // --- write x as [.., D, 2] real pairs: 8 complex = 4 float4, coalesced ---
    float* op = out + 2 * goff;
#pragma unroll
    for (int j = 0; j < 4; ++j) {
        *reinterpret_cast<float4*>(op + 4 * j) =
            make_float4(xr[2 * j], xi[2 * j], xr[2 * j + 1], xi[2 * j + 1]);
    }
}

extern "C" void kernel_launch(void* const* d_in, const int* in_sizes, int n_in,
                              void* d_out, int out_size, void* d_ws, size_t ws_size,
                              hipStream_t stream) {
    const float* psi_r = (const float*)d_in[0];
    const float* psi_i = (const float*)d_in[1];
    const float* alpha = (const float*)d_in[2];
    const float* sw = (const float*)d_in[3];
    const float* pot = (const float*)d_in[4];
    float* out = (float*)d_out;
    const int rows = in_sizes[0] / DD;   // B*S = 8192
    cayley_kernel<<<dim3(rows / 2), dim3(256), 0, stream>>>(psi_r, psi_i, alpha, sw, pot, out);
}